// Round 20
// baseline (248.917 us; speedup 1.0000x reference)
//
#include <hip/hip_runtime.h>
#include <math.h>

#define DD 8
#define HH 128
#define WW2 128
#define NPT 131072
#define NTOT 262144
#define NBK 16

typedef __attribute__((ext_vector_type(8))) short short8;
typedef __attribute__((ext_vector_type(4))) float f32x4;
typedef __attribute__((ext_vector_type(4))) unsigned short u16x4;
typedef __attribute__((ext_vector_type(8))) unsigned short u16x8;
typedef unsigned short u16;

// ---- workspace layout (bytes); total ws = 256 MiB ----
static const size_t OFF_P1  = 0;          // bf16 p1T [b][64][NPT]
static const size_t OFF_P2  = 33554432;   // bf16 p2T [b][64][NPT]
static const size_t OFF_V   = 67108864;   // bf16 vT  [b][64][NPT] (channel-planar)
static const size_t OFF_PW  = 100663296;  // packed Wv frags (4096 u16)
static const size_t OFF_PM  = 100687872;  // 8192 packed M frags
static const size_t OFF_FLAG= 100704256;  // 4
static const size_t OFF_CW  = 100704768;  // canonical weights (fp32)
static const size_t OFF_PART= 134217728;  // fp32 partials (disjoint)
// float offsets inside the OFF_PART region:
#define SP_F    0          // [NBK][2][4096] = 131072 floats (S partial buckets)
#define WQ_F    131072     // canonical Wq fp32 (4096)
#define WK_F    135168     // canonical Wk fp32 (4096)
// cw float offsets:
#define CW_WPROJ 0
#define CW_WPOS1 4096
#define CW_WPOS2 5824
#define CW_RESC  7552
#define CW_BPROJ 7556

__device__ __forceinline__ float bf2f(u16 u){
  unsigned int x = ((unsigned int)u) << 16;
  return __builtin_bit_cast(float, x);
}
__device__ __forceinline__ u16 f2bf(float f){
  unsigned int x = __builtin_bit_cast(unsigned int, f);
  unsigned int r = (x + 0x7fffu + ((x >> 16) & 1u)) >> 16;
  return (u16)r;
}

// fast exact-GELU via Abramowitz-Stegun 7.1.26 erf (|err| <= 1.5e-7, << bf16 ulp)
__device__ __forceinline__ float fgelu(float o){
  float z  = o * 0.70710678118654752f;
  float az = fabsf(z);
  float t1 = __builtin_amdgcn_rcpf(fmaf(0.3275911f, az, 1.f));
  float poly = t1 * fmaf(t1, fmaf(t1, fmaf(t1, fmaf(t1, 1.061405429f,
               -1.453152027f), 1.421413741f), -0.284496736f), 0.254829592f);
  float ex = __expf(-z * z);
  float er = 1.f - poly * ex;
  er = (z < 0.f) ? -er : er;
  return 0.5f * o * (1.f + er);
}

__device__ __forceinline__ int probe_isf32(const void* x, int t){
  u16 u = ((const u16*)x)[2 * (t & 63)];
  int e = (u >> 7) & 0xFF;
  int plaus = (u == 0) || (u == 0x8000u) || (e >= 100 && e <= 130);
  unsigned long long m = __ballot(plaus);
  return (__popcll(m) < 48) ? 1 : 0;
}

// ---- probe dtype, canonicalize weights, zero S buckets, pack Wv frags ----
__global__ __launch_bounds__(256) void k_prep(const void* __restrict__ x,
    const void* __restrict__ Wproj, const void* __restrict__ rescale,
    const void* __restrict__ bproj, const void* __restrict__ Wpos1,
    const void* __restrict__ Wpos2, const void* __restrict__ Wq,
    const void* __restrict__ Wk, const void* __restrict__ Wv,
    int* __restrict__ flag, float* __restrict__ cw, float* __restrict__ gpart,
    u16* __restrict__ packW){
  __shared__ int sflag;
  int t = threadIdx.x, blk = blockIdx.x;
  if (t < 64){
    int f = probe_isf32(x, t);
    if (t == 0) sflag = f;
  }
  __syncthreads();
  int isf32 = sflag;
  if (blk < 32){
    for (int i = blk * 4096 + t; i < (blk + 1) * 4096; i += 256)
      gpart[i] = 0.f;                    // 32 x 4096 = 131072 (Sp, NBK=16)
    if (blk == 0){
      if (t == 0) *flag = isf32;
      auto conv = [&](const void* src, float* dst, int n){
        for (int i = t; i < n; i += 256)
          dst[i] = isf32 ? ((const float*)src)[i] : bf2f(((const u16*)src)[i]);
      };
      conv(Wproj, cw + CW_WPROJ, 4096);
      conv(Wpos1, cw + CW_WPOS1, 1728);
      conv(Wpos2, cw + CW_WPOS2, 1728);
      conv(rescale, cw + CW_RESC, 4);
      conv(bproj,   cw + CW_BPROJ, 64);
      conv(Wq, gpart + WQ_F, 4096);
      conv(Wk, gpart + WK_F, 4096);
    }
  } else {
    int o = (blk - 32) * 256 + t;        // 16*256 = 4096
    int f = o >> 9, l = (o >> 3) & 63, j = o & 7;
    int tt = f >> 1, s = f & 1;
    int k = s * 32 + (l >> 4) * 8 + j;
    int n = tt * 16 + (l & 15);
    int idx = k * 64 + n;
    float val = isf32 ? ((const float*)Wv)[idx] : bf2f(((const u16*)Wv)[idx]);
    packW[o] = f2bf(val);
  }
}

__device__ __forceinline__ short8 ld8_adapt(const void* p, size_t idx, int isf32){
  if (!isf32) return *(const short8*)((const u16*)p + idx);
  const float4* f = (const float4*)((const float*)p + idx);
  float4 u = f[0], v2 = f[1];
  short8 r;
  r[0] = (short)f2bf(u.x);  r[1] = (short)f2bf(u.y);
  r[2] = (short)f2bf(u.z);  r[3] = (short)f2bf(u.w);
  r[4] = (short)f2bf(v2.x); r[5] = (short)f2bf(v2.y);
  r[6] = (short)f2bf(v2.z); r[7] = (short)f2bf(v2.w);
  return r;
}

// ---- V GEMM + S = X^T X; 512 threads, 1024 positions/block, grid 256 ----
// Reordered: vT stores issue AFTER both barriers (drain deferred to next
// iteration's first barrier, covered by S-MFMAs + next loads). The compiler's
// vmcnt(0)-before-s_barrier drain was a fixed serial cost per subtile —
// consistent with k_qkv's measured occupancy-invariance (r13).
__global__ __launch_bounds__(512) void k_qkv(const void* __restrict__ x,
                                             const int* __restrict__ flag,
                                             const u16* __restrict__ packW,
                                             u16* __restrict__ vT,
                                             float* __restrict__ Sp){
  __shared__ u16 sXT[64][136];   // [ch][pos 0..127], pad 128->136
  int isf32 = *flag;
  int wave = threadIdx.x >> 6, lane = threadIdx.x & 63;
  int m = lane & 15, quad = lane >> 4;
  const short8* bw = (const short8*)packW;
  short8 bv[8];
#pragma unroll
  for (int f = 0; f < 8; f++) bv[f] = bw[f * 64 + lane];
  int c1 = wave >> 1, c2p = (wave & 1) * 2;
  f32x4 aS[2];
  aS[0] = (f32x4)(0.f); aS[1] = (f32x4)(0.f);

  int pbase = blockIdx.x * 1024;
  int b = pbase >> 17;

  for (int s = 0; s < 8; s++){
    int p0 = pbase + s * 128 + wave * 16;
    size_t rowbase = (size_t)(p0 + m) * 64;
    short8 a0 = ld8_adapt(x, rowbase + quad * 8, isf32);
    short8 a1 = ld8_adapt(x, rowbase + 32 + quad * 8, isf32);
    // barrier phase first: prev iteration's vT stores drain here, covered
    // by the prev S-MFMA phase + this iteration's loads.
    if (s) __syncthreads();
#pragma unroll
    for (int j = 0; j < 8; j++){
      sXT[quad * 8 + j][wave * 16 + m]      = (u16)a0[j];
      sXT[32 + quad * 8 + j][wave * 16 + m] = (u16)a1[j];
    }
    __syncthreads();
    // V = x @ Wv  (pure register work; stores issue after all barriers)
    f32x4 av[4];
#pragma unroll
    for (int t = 0; t < 4; t++) av[t] = (f32x4)(0.f);
#pragma unroll
    for (int t = 0; t < 4; t++){
      av[t] = __builtin_amdgcn_mfma_f32_16x16x32_bf16(a0, bv[t * 2 + 0], av[t], 0, 0, 0);
      av[t] = __builtin_amdgcn_mfma_f32_16x16x32_bf16(a1, bv[t * 2 + 1], av[t], 0, 0, 0);
    }
    int nloc = p0 & (NPT - 1);
#pragma unroll
    for (int t = 0; t < 4; t++){
      u16x4 pk;
#pragma unroll
      for (int r = 0; r < 4; r++) pk[r] = f2bf(av[t][r]);
      *(u16x4*)(vT + ((size_t)(b * 64 + t * 16 + m)) * NPT + nloc + quad * 4) = pk;
    }
    // S MFMAs from LDS (overlaps with in-flight vT stores)
#pragma unroll
    for (int ks = 0; ks < 4; ks++){
      short8 fA  = *(const short8*)&sXT[c1 * 16 + m][ks * 32 + quad * 8];
      short8 fB0 = *(const short8*)&sXT[(c2p + 0) * 16 + m][ks * 32 + quad * 8];
      short8 fB1 = *(const short8*)&sXT[(c2p + 1) * 16 + m][ks * 32 + quad * 8];
      aS[0] = __builtin_amdgcn_mfma_f32_16x16x32_bf16(fA, fB0, aS[0], 0, 0, 0);
      aS[1] = __builtin_amdgcn_mfma_f32_16x16x32_bf16(fA, fB1, aS[1], 0, 0, 0);
    }
  }
  int bk = blockIdx.x & (NBK - 1);
  float* Sb = Sp + (size_t)(bk * 2 + b) * 4096;
#pragma unroll
  for (int tt = 0; tt < 2; tt++)
#pragma unroll
    for (int r = 0; r < 4; r++)
      atomicAdd(&Sb[(c1 * 16 + quad * 4 + r) * 64 + (c2p + tt) * 16 + m], aS[tt][r]);
}

// ---- per-(b,head): G_h = Wk_h^T S Wq_h, norms, softmax, M_h = A@Wproj_h,
//      pack M_h directly into its disjoint slice of packM (8 blocks) ----
__global__ __launch_bounds__(256) void k_attn_h(const float* __restrict__ Sp,
    const float* __restrict__ wqk, const float* __restrict__ cw,
    u16* __restrict__ packM){
  __shared__ float sS[64 * 65];
  __shared__ float sWh[1024];
  __shared__ float sT[1024];
  __shared__ float sG[256];
  __shared__ float sA[256];
  __shared__ float sNq[16], sNk[16];
  int blk = blockIdx.x, t = threadIdx.x;
  int b = blk >> 2, h = blk & 3;
  for (int i = t; i < 4096; i += 256){
    float s = 0.f;
#pragma unroll
    for (int bk = 0; bk < NBK; bk++) s += Sp[(size_t)(bk * 2 + b) * 4096 + i];
    sS[(i >> 6) * 65 + (i & 63)] = s;
  }
  for (int i = t; i < 1024; i += 256)
    sWh[i] = wqk[(i >> 4) * 64 + h * 16 + (i & 15)];        // Wq_h
  __syncthreads();
  int cc = t & 63, eg = t >> 6;
  {
    float a0 = 0.f, a1 = 0.f, a2 = 0.f, a3 = 0.f;           // T = S @ Wq_h
    for (int c2 = 0; c2 < 64; c2++){
      float sv = sS[cc * 65 + c2];
      a0 = fmaf(sv, sWh[c2 * 16 + eg * 4 + 0], a0);
      a1 = fmaf(sv, sWh[c2 * 16 + eg * 4 + 1], a1);
      a2 = fmaf(sv, sWh[c2 * 16 + eg * 4 + 2], a2);
      a3 = fmaf(sv, sWh[c2 * 16 + eg * 4 + 3], a3);
    }
    sT[cc * 16 + eg * 4 + 0] = a0;
    sT[cc * 16 + eg * 4 + 1] = a1;
    sT[cc * 16 + eg * 4 + 2] = a2;
    sT[cc * 16 + eg * 4 + 3] = a3;
  }
  __syncthreads();
  if (t < 16){                             // nq_e = <wq_e, T_e>
    float a = 0.f;
    for (int c = 0; c < 64; c++) a += sWh[c * 16 + t] * sT[c * 16 + t];
    sNq[t] = a;
  }
  __syncthreads();
  for (int i = t; i < 1024; i += 256)
    sWh[i] = wqk[4096 + (i >> 4) * 64 + h * 16 + (i & 15)]; // Wk_h
  __syncthreads();
  {
    int d = t >> 4, e = t & 15;            // G[d][e] = sum_c wk[c][d] T[c][e]
    float a = 0.f;
    for (int c = 0; c < 64; c++) a += sWh[c * 16 + d] * sT[c * 16 + e];
    sG[d * 16 + e] = a;
  }
  __syncthreads();
  {
    float a0 = 0.f, a1 = 0.f, a2 = 0.f, a3 = 0.f;   // T2 = S @ wk_h
    for (int c2 = 0; c2 < 64; c2++){
      float sv = sS[cc * 65 + c2];
      a0 = fmaf(sv, sWh[c2 * 16 + eg * 4 + 0], a0);
      a1 = fmaf(sv, sWh[c2 * 16 + eg * 4 + 1], a1);
      a2 = fmaf(sv, sWh[c2 * 16 + eg * 4 + 2], a2);
      a3 = fmaf(sv, sWh[c2 * 16 + eg * 4 + 3], a3);
    }
    __syncthreads();
    sT[cc * 16 + eg * 4 + 0] = a0;
    sT[cc * 16 + eg * 4 + 1] = a1;
    sT[cc * 16 + eg * 4 + 2] = a2;
    sT[cc * 16 + eg * 4 + 3] = a3;
  }
  __syncthreads();
  if (t < 16){                             // nk_d
    float a = 0.f;
    for (int c = 0; c < 64; c++) a += sWh[c * 16 + t] * sT[c * 16 + t];
    sNk[t] = a;
  }
  __syncthreads();
  // stage Wproj_h [d][c] into sT while t<16 do softmax
  for (int i = t; i < 1024; i += 256)
    sT[i] = cw[CW_WPROJ + (h * 16 + (i >> 6)) * 64 + (i & 63)];
  if (t < 16){
    int d = t;
    float nk = fmaxf(sqrtf(sNk[d]), 1e-12f);
    float rs = cw[CW_RESC + h];
    float lg[16]; float mx = -1e30f;
#pragma unroll
    for (int e = 0; e < 16; e++){
      float nq = fmaxf(sqrtf(sNq[e]), 1e-12f);
      float L = sG[d * 16 + e] / (nk * nq) * rs;
      lg[e] = L; mx = fmaxf(mx, L);
    }
    float sum = 0.f;
#pragma unroll
    for (int e = 0; e < 16; e++){ lg[e] = expf(lg[e] - mx); sum += lg[e]; }
    float inv = 1.f / sum;
#pragma unroll
    for (int e = 0; e < 16; e++) sA[d * 16 + e] = lg[e] * inv;
  }
  __syncthreads();
  // M_h[e][c] = sum_d A[d][e] * Wproj[h*16+d][c]; write packed frag slice.
#pragma unroll
  for (int q = 0; q < 4; q++){
    int i = q * 256 + t;                   // t4(4) | lhi(2) | llo(16) | j(8)
    int t4 = i >> 8, lhi = (i >> 7) & 1, llo = (i >> 3) & 15, j = i & 7;
    int e = lhi * 8 + j, c = t4 * 16 + llo;
    float acc = 0.f;
#pragma unroll
    for (int d = 0; d < 16; d++) acc += sA[d * 16 + e] * sT[d * 64 + c];
    int f = t4 * 2 + (h >> 1);
    int l = (2 * (h & 1) + lhi) * 16 + llo;
    packM[b * 4096 + f * 512 + l * 8 + j] = f2bf(acc);
  }
}

// ---- depthwise 3x3x3 conv: 2z x 2y x 8x per thread, load-first ----
// Invalid rows zeroed at load (cndmask, no msk[] array); (256,4) is the
// measured optimum — r16/r17/r18 showed any other bound spills or serializes.
template <bool GELU>
__global__ __launch_bounds__(256, 4) void k_dwconv(const u16* __restrict__ src,
    const float* __restrict__ wpos, u16* __restrict__ dst){
  int xi = threadIdx.x & 15, ty = threadIdx.x >> 4;
  int zp = ty >> 2, yq = ty & 3;
  int x0 = xi * 8;
  int c  = blockIdx.x;                  // 64
  int y0 = blockIdx.y * 8 + yq * 2;     // 16 y-windows of 8
  int b  = blockIdx.z;
  int z0 = zp * 2;
  const float* wg = wpos + c * 27;      // wave-uniform -> SGPR
  float w27[27];
#pragma unroll
  for (int i = 0; i < 27; i++) w27[i] = wg[i];
  const u16* plane = src + (size_t)(b * 64 + c) * NPT;

  short8 raw[16];
  const short8 zz8 = (short8)0;
#pragma unroll
  for (int iz = 0; iz < 4; iz++){
    int zz = z0 - 1 + iz;
    int zc = zz < 0 ? 0 : (zz > DD - 1 ? DD - 1 : zz);
    int zv = (zz == zc);
#pragma unroll
    for (int iy = 0; iy < 4; iy++){
      int yy = y0 - 1 + iy;
      int yc = yy < 0 ? 0 : (yy > HH - 1 ? HH - 1 : yy);
      short8 v = *(const short8*)(plane + zc * 16384 + yc * 128 + x0);
      raw[iz * 4 + iy] = (zv && yy == yc) ? v : zz8;
    }
  }

  float acc[2][2][8];
#pragma unroll
  for (int dz = 0; dz < 2; dz++)
#pragma unroll
    for (int dy = 0; dy < 2; dy++)
#pragma unroll
      for (int xx = 0; xx < 8; xx++) acc[dz][dy][xx] = 0.f;

#pragma unroll
  for (int iz = 0; iz < 4; iz++){
#pragma unroll
    for (int iy = 0; iy < 4; iy++){
      short8 mid = raw[iz * 4 + iy];
      float row[10];
#pragma unroll
      for (int e = 0; e < 8; e++) row[1 + e] = bf2f((u16)mid[e]);
      float lf = __shfl_up(row[8], 1);      // left neighbor's x0+7
      float rg = __shfl_down(row[1], 1);    // right neighbor's x0
      row[0] = (xi > 0)  ? lf : 0.f;
      row[9] = (xi < 15) ? rg : 0.f;
#pragma unroll
      for (int dzi = 0; dzi < 2; dzi++){
        int kd = iz - dzi;                   // compile-time after unroll
        if (kd < 0 || kd > 2) continue;
#pragma unroll
        for (int dyi = 0; dyi < 2; dyi++){
          int kh = iy - dyi;
          if (kh < 0 || kh > 2) continue;
#pragma unroll
          for (int kw = 0; kw < 3; kw++){
            float w = w27[kd * 9 + kh * 3 + kw];
#pragma unroll
            for (int xx = 0; xx < 8; xx++)
              acc[dzi][dyi][xx] = fmaf(row[xx + kw], w, acc[dzi][dyi][xx]);
          }
        }
      }
    }
  }
#pragma unroll
  for (int dzi = 0; dzi < 2; dzi++){
    int zo = z0 + dzi;
#pragma unroll
    for (int dyi = 0; dyi < 2; dyi++){
      int yo = y0 + dyi;
      u16x8 pk;
#pragma unroll
      for (int xx = 0; xx < 8; xx++){
        float o = acc[dzi][dyi][xx];
        if (GELU) o = fgelu(o);
        pk[xx] = f2bf(o);
      }
      *(u16x8*)(dst + (size_t)(b * 64 + c) * NPT + zo * 16384 + yo * 128 + x0) = pk;
    }
  }
}

// ---- final: vT @ M + bproj + conv2 output -> fp32 out ----
// Stages BOTH vT and p2T tiles into LDS with coalesced loads; A-fragments
// built from LDS columns.
__global__ __launch_bounds__(256) void k_final(const u16* __restrict__ vT,
                                               const u16* __restrict__ packM,
                                               const float* __restrict__ bprojf,
                                               const u16* __restrict__ p2T,
                                               float* __restrict__ out){
  __shared__ u16 sP2[64][72];     // [ch][pos 0..63]
  __shared__ u16 sVt[64][72];     // [ch][pos 0..63]
  __shared__ float sOut[64][68];  // [pos][ch]
  int tid = threadIdx.x;
  int wave = tid >> 6, lane = tid & 63;
  int m = lane & 15, quad = lane >> 4;
  int pbase = blockIdx.x * 64;
  int b = pbase >> 17;
  int nloc = pbase & (NPT - 1);
  {
    int c = tid >> 2, po = (tid & 3) * 16;
    const u16* s1 = p2T + (size_t)(b * 64 + c) * NPT + nloc + po;
    *(u16x8*)&sP2[c][po]     = *(const u16x8*)s1;
    *(u16x8*)&sP2[c][po + 8] = *(const u16x8*)(s1 + 8);
    const u16* s2 = vT + (size_t)(b * 64 + c) * NPT + nloc + po;
    *(u16x8*)&sVt[c][po]     = *(const u16x8*)s2;
    *(u16x8*)&sVt[c][po + 8] = *(const u16x8*)(s2 + 8);
  }
  __syncthreads();
  int lp = wave * 16 + m;
  short8 a0, a1;
#pragma unroll
  for (int j = 0; j < 8; j++){
    a0[j] = (short)sVt[quad * 8 + j][lp];
    a1[j] = (short)sVt[32 + quad * 8 + j][lp];
  }
  const short8* bm = (const short8*)(packM + (size_t)b * 4096);
  f32x4 acc[4];
#pragma unroll
  for (int t = 0; t < 4; t++) acc[t] = (f32x4)(0.f);
#pragma unroll
  for (int t = 0; t < 4; t++){
    short8 b0 = bm[(t * 2 + 0) * 64 + lane];
    short8 b1 = bm[(t * 2 + 1) * 64 + lane];
    acc[t] = __builtin_amdgcn_mfma_f32_16x16x32_bf16(a0, b0, acc[t], 0, 0, 0);
    acc[t] = __builtin_amdgcn_mfma_f32_16x16x32_bf16(a1, b1, acc[t], 0, 0, 0);
  }
#pragma unroll
  for (int t = 0; t < 4; t++){
    int c = t * 16 + m;
    float bias = bprojf[c];
#pragma unroll
    for (int r = 0; r < 4; r++){
      int op = wave * 16 + quad * 4 + r;
      sOut[op][c] = acc[t][r] + bias + bf2f(sP2[c][op]);
    }
  }
  __syncthreads();
  int hi = tid >> 4, lo = tid & 15;
#pragma unroll
  for (int k = 0; k < 4; k++){
    int pos = k * 16 + hi;
    int c0  = lo * 4;
    float4 v = *(const float4*)&sOut[pos][c0];
    *(float4*)(out + (size_t)(pbase + pos) * 64 + c0) = v;
  }
}

extern "C" void kernel_launch(void* const* d_in, const int* in_sizes, int n_in,
                              void* d_out, int out_size, void* d_ws, size_t ws_size,
                              hipStream_t stream){
  (void)in_sizes; (void)n_in; (void)out_size; (void)ws_size;
  const void* x      = d_in[0];
  const void* Wq     = d_in[1];
  const void* Wk     = d_in[2];
  const void* Wv     = d_in[3];
  const void* rescale= d_in[4];
  const void* Wproj  = d_in[5];
  const void* bproj  = d_in[6];
  const void* Wpos1  = d_in[7];
  const void* Wpos2  = d_in[8];

  char* ws = (char*)d_ws;
  u16* p1T   = (u16*)(ws + OFF_P1);
  u16* p2T   = (u16*)(ws + OFF_P2);
  u16* vT    = (u16*)(ws + OFF_V);
  u16* packW = (u16*)(ws + OFF_PW);
  u16* packM = (u16*)(ws + OFF_PM);
  int* flag  = (int*)(ws + OFF_FLAG);
  float* cw  = (float*)(ws + OFF_CW);
  float* part= (float*)(ws + OFF_PART);
  float* Sp  = part + SP_F;
  float* wqk = part + WQ_F;
  float* out = (float*)d_out;

  k_prep<<<48, 256, 0, stream>>>(x, Wproj, rescale, bproj, Wpos1, Wpos2, Wq, Wk, Wv,
                                 flag, cw, Sp, packW);
  k_qkv<<<NTOT / 1024, 512, 0, stream>>>(x, flag, packW, vT, Sp);
  k_attn_h<<<8, 256, 0, stream>>>(Sp, wqk, cw, packM);
  k_dwconv<true><<<dim3(64, 16, 2), 256, 0, stream>>>(vT, cw + CW_WPOS1, p1T);
  k_dwconv<false><<<dim3(64, 16, 2), 256, 0, stream>>>(p1T, cw + CW_WPOS2, p2T);
  k_final<<<NTOT / 64, 256, 0, stream>>>(vT, packM, cw + CW_BPROJ, p2T, out);
}

// Round 21
// 242.684 us; speedup vs baseline: 1.0257x; 1.0257x over previous
//
#include <hip/hip_runtime.h>
#include <math.h>

#define DD 8
#define HH 128
#define WW2 128
#define NPT 131072
#define NTOT 262144
#define NBK 16

typedef __attribute__((ext_vector_type(8))) short short8;
typedef __attribute__((ext_vector_type(4))) float f32x4;
typedef __attribute__((ext_vector_type(4))) unsigned short u16x4;
typedef __attribute__((ext_vector_type(8))) unsigned short u16x8;
typedef unsigned short u16;

// ---- workspace layout (bytes); total ws = 256 MiB ----
static const size_t OFF_P1  = 0;          // bf16 p1T [b][64][NPT]
static const size_t OFF_P2  = 33554432;   // bf16 p2T [b][64][NPT]
static const size_t OFF_V   = 67108864;   // bf16 vT  [b][64][NPT] (channel-planar)
static const size_t OFF_PW  = 100663296;  // packed Wv frags (4096 u16)
static const size_t OFF_PM  = 100687872;  // 8192 packed M frags
static const size_t OFF_FLAG= 100704256;  // 4
static const size_t OFF_CW  = 100704768;  // canonical weights (fp32)
static const size_t OFF_PART= 134217728;  // fp32 partials (disjoint)
// float offsets inside the OFF_PART region:
#define SP_F    0          // [NBK][2][4096] = 131072 floats (S partial buckets)
#define WQ_F    131072     // canonical Wq fp32 (4096)
#define WK_F    135168     // canonical Wk fp32 (4096)
// cw float offsets:
#define CW_WPROJ 0
#define CW_WPOS1 4096
#define CW_WPOS2 5824
#define CW_RESC  7552
#define CW_BPROJ 7556

__device__ __forceinline__ float bf2f(u16 u){
  unsigned int x = ((unsigned int)u) << 16;
  return __builtin_bit_cast(float, x);
}
__device__ __forceinline__ u16 f2bf(float f){
  unsigned int x = __builtin_bit_cast(unsigned int, f);
  unsigned int r = (x + 0x7fffu + ((x >> 16) & 1u)) >> 16;
  return (u16)r;
}

// fast exact-GELU via Abramowitz-Stegun 7.1.26 erf (|err| <= 1.5e-7, << bf16 ulp)
__device__ __forceinline__ float fgelu(float o){
  float z  = o * 0.70710678118654752f;
  float az = fabsf(z);
  float t1 = __builtin_amdgcn_rcpf(fmaf(0.3275911f, az, 1.f));
  float poly = t1 * fmaf(t1, fmaf(t1, fmaf(t1, fmaf(t1, 1.061405429f,
               -1.453152027f), 1.421413741f), -0.284496736f), 0.254829592f);
  float ex = __expf(-z * z);
  float er = 1.f - poly * ex;
  er = (z < 0.f) ? -er : er;
  return 0.5f * o * (1.f + er);
}

__device__ __forceinline__ int probe_isf32(const void* x, int t){
  u16 u = ((const u16*)x)[2 * (t & 63)];
  int e = (u >> 7) & 0xFF;
  int plaus = (u == 0) || (u == 0x8000u) || (e >= 100 && e <= 130);
  unsigned long long m = __ballot(plaus);
  return (__popcll(m) < 48) ? 1 : 0;
}

// ---- probe dtype, canonicalize weights, zero S buckets, pack Wv frags ----
__global__ __launch_bounds__(256) void k_prep(const void* __restrict__ x,
    const void* __restrict__ Wproj, const void* __restrict__ rescale,
    const void* __restrict__ bproj, const void* __restrict__ Wpos1,
    const void* __restrict__ Wpos2, const void* __restrict__ Wq,
    const void* __restrict__ Wk, const void* __restrict__ Wv,
    int* __restrict__ flag, float* __restrict__ cw, float* __restrict__ gpart,
    u16* __restrict__ packW){
  __shared__ int sflag;
  int t = threadIdx.x, blk = blockIdx.x;
  if (t < 64){
    int f = probe_isf32(x, t);
    if (t == 0) sflag = f;
  }
  __syncthreads();
  int isf32 = sflag;
  if (blk < 32){
    for (int i = blk * 4096 + t; i < (blk + 1) * 4096; i += 256)
      gpart[i] = 0.f;                    // 32 x 4096 = 131072 (Sp, NBK=16)
    if (blk == 0){
      if (t == 0) *flag = isf32;
      auto conv = [&](const void* src, float* dst, int n){
        for (int i = t; i < n; i += 256)
          dst[i] = isf32 ? ((const float*)src)[i] : bf2f(((const u16*)src)[i]);
      };
      conv(Wproj, cw + CW_WPROJ, 4096);
      conv(Wpos1, cw + CW_WPOS1, 1728);
      conv(Wpos2, cw + CW_WPOS2, 1728);
      conv(rescale, cw + CW_RESC, 4);
      conv(bproj,   cw + CW_BPROJ, 64);
      conv(Wq, gpart + WQ_F, 4096);
      conv(Wk, gpart + WK_F, 4096);
    }
  } else {
    int o = (blk - 32) * 256 + t;        // 16*256 = 4096
    int f = o >> 9, l = (o >> 3) & 63, j = o & 7;
    int tt = f >> 1, s = f & 1;
    int k = s * 32 + (l >> 4) * 8 + j;
    int n = tt * 16 + (l & 15);
    int idx = k * 64 + n;
    float val = isf32 ? ((const float*)Wv)[idx] : bf2f(((const u16*)Wv)[idx]);
    packW[o] = f2bf(val);
  }
}

__device__ __forceinline__ short8 ld8_adapt(const void* p, size_t idx, int isf32){
  if (!isf32) return *(const short8*)((const u16*)p + idx);
  const float4* f = (const float4*)((const float*)p + idx);
  float4 u = f[0], v2 = f[1];
  short8 r;
  r[0] = (short)f2bf(u.x);  r[1] = (short)f2bf(u.y);
  r[2] = (short)f2bf(u.z);  r[3] = (short)f2bf(u.w);
  r[4] = (short)f2bf(v2.x); r[5] = (short)f2bf(v2.y);
  r[6] = (short)f2bf(v2.z); r[7] = (short)f2bf(v2.w);
  return r;
}

// ---- V GEMM + S = X^T X; 512 threads, 1024 positions/block, grid 256 ----
__global__ __launch_bounds__(512) void k_qkv(const void* __restrict__ x,
                                             const int* __restrict__ flag,
                                             const u16* __restrict__ packW,
                                             u16* __restrict__ vT,
                                             float* __restrict__ Sp){
  __shared__ u16 sXT[64][136];   // [ch][pos 0..127], pad 128->136
  int isf32 = *flag;
  int wave = threadIdx.x >> 6, lane = threadIdx.x & 63;
  int m = lane & 15, quad = lane >> 4;
  const short8* bw = (const short8*)packW;
  short8 bv[8];
#pragma unroll
  for (int f = 0; f < 8; f++) bv[f] = bw[f * 64 + lane];
  int c1 = wave >> 1, c2p = (wave & 1) * 2;
  f32x4 aS[2];
  aS[0] = (f32x4)(0.f); aS[1] = (f32x4)(0.f);

  int pbase = blockIdx.x * 1024;
  int b = pbase >> 17;

  for (int s = 0; s < 8; s++){
    int p0 = pbase + s * 128 + wave * 16;
    size_t rowbase = (size_t)(p0 + m) * 64;
    short8 a0 = ld8_adapt(x, rowbase + quad * 8, isf32);
    short8 a1 = ld8_adapt(x, rowbase + 32 + quad * 8, isf32);
    f32x4 av[4];
#pragma unroll
    for (int t = 0; t < 4; t++) av[t] = (f32x4)(0.f);
#pragma unroll
    for (int t = 0; t < 4; t++){
      av[t] = __builtin_amdgcn_mfma_f32_16x16x32_bf16(a0, bv[t * 2 + 0], av[t], 0, 0, 0);
      av[t] = __builtin_amdgcn_mfma_f32_16x16x32_bf16(a1, bv[t * 2 + 1], av[t], 0, 0, 0);
    }
    int nloc = p0 & (NPT - 1);
#pragma unroll
    for (int t = 0; t < 4; t++){
      u16x4 pk;
#pragma unroll
      for (int r = 0; r < 4; r++) pk[r] = f2bf(av[t][r]);
      *(u16x4*)(vT + ((size_t)(b * 64 + t * 16 + m)) * NPT + nloc + quad * 4) = pk;
    }
    if (s) __syncthreads();
#pragma unroll
    for (int j = 0; j < 8; j++){
      sXT[quad * 8 + j][wave * 16 + m]      = (u16)a0[j];
      sXT[32 + quad * 8 + j][wave * 16 + m] = (u16)a1[j];
    }
    __syncthreads();
#pragma unroll
    for (int ks = 0; ks < 4; ks++){
      short8 fA  = *(const short8*)&sXT[c1 * 16 + m][ks * 32 + quad * 8];
      short8 fB0 = *(const short8*)&sXT[(c2p + 0) * 16 + m][ks * 32 + quad * 8];
      short8 fB1 = *(const short8*)&sXT[(c2p + 1) * 16 + m][ks * 32 + quad * 8];
      aS[0] = __builtin_amdgcn_mfma_f32_16x16x32_bf16(fA, fB0, aS[0], 0, 0, 0);
      aS[1] = __builtin_amdgcn_mfma_f32_16x16x32_bf16(fA, fB1, aS[1], 0, 0, 0);
    }
  }
  int bk = blockIdx.x & (NBK - 1);
  float* Sb = Sp + (size_t)(bk * 2 + b) * 4096;
#pragma unroll
  for (int tt = 0; tt < 2; tt++)
#pragma unroll
    for (int r = 0; r < 4; r++)
      atomicAdd(&Sb[(c1 * 16 + quad * 4 + r) * 64 + (c2p + tt) * 16 + m], aS[tt][r]);
}

// ---- per-(b,head): G_h = Wk_h^T S Wq_h, norms, softmax, M_h = A@Wproj_h,
//      pack M_h directly into its disjoint slice of packM (8 blocks) ----
__global__ __launch_bounds__(256) void k_attn_h(const float* __restrict__ Sp,
    const float* __restrict__ wqk, const float* __restrict__ cw,
    u16* __restrict__ packM){
  __shared__ float sS[64 * 65];
  __shared__ float sWh[1024];
  __shared__ float sT[1024];
  __shared__ float sG[256];
  __shared__ float sA[256];
  __shared__ float sNq[16], sNk[16];
  int blk = blockIdx.x, t = threadIdx.x;
  int b = blk >> 2, h = blk & 3;
  for (int i = t; i < 4096; i += 256){
    float s = 0.f;
#pragma unroll
    for (int bk = 0; bk < NBK; bk++) s += Sp[(size_t)(bk * 2 + b) * 4096 + i];
    sS[(i >> 6) * 65 + (i & 63)] = s;
  }
  for (int i = t; i < 1024; i += 256)
    sWh[i] = wqk[(i >> 4) * 64 + h * 16 + (i & 15)];        // Wq_h
  __syncthreads();
  int cc = t & 63, eg = t >> 6;
  {
    float a0 = 0.f, a1 = 0.f, a2 = 0.f, a3 = 0.f;           // T = S @ Wq_h
    for (int c2 = 0; c2 < 64; c2++){
      float sv = sS[cc * 65 + c2];
      a0 = fmaf(sv, sWh[c2 * 16 + eg * 4 + 0], a0);
      a1 = fmaf(sv, sWh[c2 * 16 + eg * 4 + 1], a1);
      a2 = fmaf(sv, sWh[c2 * 16 + eg * 4 + 2], a2);
      a3 = fmaf(sv, sWh[c2 * 16 + eg * 4 + 3], a3);
    }
    sT[cc * 16 + eg * 4 + 0] = a0;
    sT[cc * 16 + eg * 4 + 1] = a1;
    sT[cc * 16 + eg * 4 + 2] = a2;
    sT[cc * 16 + eg * 4 + 3] = a3;
  }
  __syncthreads();
  if (t < 16){                             // nq_e = <wq_e, T_e>
    float a = 0.f;
    for (int c = 0; c < 64; c++) a += sWh[c * 16 + t] * sT[c * 16 + t];
    sNq[t] = a;
  }
  __syncthreads();
  for (int i = t; i < 1024; i += 256)
    sWh[i] = wqk[4096 + (i >> 4) * 64 + h * 16 + (i & 15)]; // Wk_h
  __syncthreads();
  {
    int d = t >> 4, e = t & 15;            // G[d][e] = sum_c wk[c][d] T[c][e]
    float a = 0.f;
    for (int c = 0; c < 64; c++) a += sWh[c * 16 + d] * sT[c * 16 + e];
    sG[d * 16 + e] = a;
  }
  __syncthreads();
  {
    float a0 = 0.f, a1 = 0.f, a2 = 0.f, a3 = 0.f;   // T2 = S @ wk_h
    for (int c2 = 0; c2 < 64; c2++){
      float sv = sS[cc * 65 + c2];
      a0 = fmaf(sv, sWh[c2 * 16 + eg * 4 + 0], a0);
      a1 = fmaf(sv, sWh[c2 * 16 + eg * 4 + 1], a1);
      a2 = fmaf(sv, sWh[c2 * 16 + eg * 4 + 2], a2);
      a3 = fmaf(sv, sWh[c2 * 16 + eg * 4 + 3], a3);
    }
    __syncthreads();
    sT[cc * 16 + eg * 4 + 0] = a0;
    sT[cc * 16 + eg * 4 + 1] = a1;
    sT[cc * 16 + eg * 4 + 2] = a2;
    sT[cc * 16 + eg * 4 + 3] = a3;
  }
  __syncthreads();
  if (t < 16){                             // nk_d
    float a = 0.f;
    for (int c = 0; c < 64; c++) a += sWh[c * 16 + t] * sT[c * 16 + t];
    sNk[t] = a;
  }
  __syncthreads();
  // stage Wproj_h [d][c] into sT while t<16 do softmax
  for (int i = t; i < 1024; i += 256)
    sT[i] = cw[CW_WPROJ + (h * 16 + (i >> 6)) * 64 + (i & 63)];
  if (t < 16){
    int d = t;
    float nk = fmaxf(sqrtf(sNk[d]), 1e-12f);
    float rs = cw[CW_RESC + h];
    float lg[16]; float mx = -1e30f;
#pragma unroll
    for (int e = 0; e < 16; e++){
      float nq = fmaxf(sqrtf(sNq[e]), 1e-12f);
      float L = sG[d * 16 + e] / (nk * nq) * rs;
      lg[e] = L; mx = fmaxf(mx, L);
    }
    float sum = 0.f;
#pragma unroll
    for (int e = 0; e < 16; e++){ lg[e] = expf(lg[e] - mx); sum += lg[e]; }
    float inv = 1.f / sum;
#pragma unroll
    for (int e = 0; e < 16; e++) sA[d * 16 + e] = lg[e] * inv;
  }
  __syncthreads();
  // M_h[e][c] = sum_d A[d][e] * Wproj[h*16+d][c]; write packed frag slice.
#pragma unroll
  for (int q = 0; q < 4; q++){
    int i = q * 256 + t;                   // t4(4) | lhi(2) | llo(16) | j(8)
    int t4 = i >> 8, lhi = (i >> 7) & 1, llo = (i >> 3) & 15, j = i & 7;
    int e = lhi * 8 + j, c = t4 * 16 + llo;
    float acc = 0.f;
#pragma unroll
    for (int d = 0; d < 16; d++) acc += sA[d * 16 + e] * sT[d * 64 + c];
    int f = t4 * 2 + (h >> 1);
    int l = (2 * (h & 1) + lhi) * 16 + llo;
    packM[b * 4096 + f * 512 + l * 8 + j] = f2bf(acc);
  }
}

// ---- depthwise 3x3x3 conv: 2z x 2y x 8x per thread, load-first ----
// Invalid rows zeroed at load (cndmask, no msk[] array); (256,4) is the
// measured optimum — r16/r17/r18 showed any other bound spills or serializes.
template <bool GELU>
__global__ __launch_bounds__(256, 4) void k_dwconv(const u16* __restrict__ src,
    const float* __restrict__ wpos, u16* __restrict__ dst){
  int xi = threadIdx.x & 15, ty = threadIdx.x >> 4;
  int zp = ty >> 2, yq = ty & 3;
  int x0 = xi * 8;
  int c  = blockIdx.x;                  // 64
  int y0 = blockIdx.y * 8 + yq * 2;     // 16 y-windows of 8
  int b  = blockIdx.z;
  int z0 = zp * 2;
  const float* wg = wpos + c * 27;      // wave-uniform -> SGPR
  float w27[27];
#pragma unroll
  for (int i = 0; i < 27; i++) w27[i] = wg[i];
  const u16* plane = src + (size_t)(b * 64 + c) * NPT;

  short8 raw[16];
  const short8 zz8 = (short8)0;
#pragma unroll
  for (int iz = 0; iz < 4; iz++){
    int zz = z0 - 1 + iz;
    int zc = zz < 0 ? 0 : (zz > DD - 1 ? DD - 1 : zz);
    int zv = (zz == zc);
#pragma unroll
    for (int iy = 0; iy < 4; iy++){
      int yy = y0 - 1 + iy;
      int yc = yy < 0 ? 0 : (yy > HH - 1 ? HH - 1 : yy);
      short8 v = *(const short8*)(plane + zc * 16384 + yc * 128 + x0);
      raw[iz * 4 + iy] = (zv && yy == yc) ? v : zz8;
    }
  }

  float acc[2][2][8];
#pragma unroll
  for (int dz = 0; dz < 2; dz++)
#pragma unroll
    for (int dy = 0; dy < 2; dy++)
#pragma unroll
      for (int xx = 0; xx < 8; xx++) acc[dz][dy][xx] = 0.f;

#pragma unroll
  for (int iz = 0; iz < 4; iz++){
#pragma unroll
    for (int iy = 0; iy < 4; iy++){
      short8 mid = raw[iz * 4 + iy];
      float row[10];
#pragma unroll
      for (int e = 0; e < 8; e++) row[1 + e] = bf2f((u16)mid[e]);
      float lf = __shfl_up(row[8], 1);      // left neighbor's x0+7
      float rg = __shfl_down(row[1], 1);    // right neighbor's x0
      row[0] = (xi > 0)  ? lf : 0.f;
      row[9] = (xi < 15) ? rg : 0.f;
#pragma unroll
      for (int dzi = 0; dzi < 2; dzi++){
        int kd = iz - dzi;                   // compile-time after unroll
        if (kd < 0 || kd > 2) continue;
#pragma unroll
        for (int dyi = 0; dyi < 2; dyi++){
          int kh = iy - dyi;
          if (kh < 0 || kh > 2) continue;
#pragma unroll
          for (int kw = 0; kw < 3; kw++){
            float w = w27[kd * 9 + kh * 3 + kw];
#pragma unroll
            for (int xx = 0; xx < 8; xx++)
              acc[dzi][dyi][xx] = fmaf(row[xx + kw], w, acc[dzi][dyi][xx]);
          }
        }
      }
    }
  }
#pragma unroll
  for (int dzi = 0; dzi < 2; dzi++){
    int zo = z0 + dzi;
#pragma unroll
    for (int dyi = 0; dyi < 2; dyi++){
      int yo = y0 + dyi;
      u16x8 pk;
#pragma unroll
      for (int xx = 0; xx < 8; xx++){
        float o = acc[dzi][dyi][xx];
        if (GELU) o = fgelu(o);
        pk[xx] = f2bf(o);
      }
      *(u16x8*)(dst + (size_t)(b * 64 + c) * NPT + zo * 16384 + yo * 128 + x0) = pk;
    }
  }
}

// ---- final: vT @ M + bproj + conv2 output -> fp32 out ----
// Stages BOTH vT and p2T tiles into LDS with coalesced loads; A-fragments
// built from LDS columns.
__global__ __launch_bounds__(256) void k_final(const u16* __restrict__ vT,
                                               const u16* __restrict__ packM,
                                               const float* __restrict__ bprojf,
                                               const u16* __restrict__ p2T,
                                               float* __restrict__ out){
  __shared__ u16 sP2[64][72];     // [ch][pos 0..63]
  __shared__ u16 sVt[64][72];     // [ch][pos 0..63]
  __shared__ float sOut[64][68];  // [pos][ch]
  int tid = threadIdx.x;
  int wave = tid >> 6, lane = tid & 63;
  int m = lane & 15, quad = lane >> 4;
  int pbase = blockIdx.x * 64;
  int b = pbase >> 17;
  int nloc = pbase & (NPT - 1);
  {
    int c = tid >> 2, po = (tid & 3) * 16;
    const u16* s1 = p2T + (size_t)(b * 64 + c) * NPT + nloc + po;
    *(u16x8*)&sP2[c][po]     = *(const u16x8*)s1;
    *(u16x8*)&sP2[c][po + 8] = *(const u16x8*)(s1 + 8);
    const u16* s2 = vT + (size_t)(b * 64 + c) * NPT + nloc + po;
    *(u16x8*)&sVt[c][po]     = *(const u16x8*)s2;
    *(u16x8*)&sVt[c][po + 8] = *(const u16x8*)(s2 + 8);
  }
  __syncthreads();
  int lp = wave * 16 + m;
  short8 a0, a1;
#pragma unroll
  for (int j = 0; j < 8; j++){
    a0[j] = (short)sVt[quad * 8 + j][lp];
    a1[j] = (short)sVt[32 + quad * 8 + j][lp];
  }
  const short8* bm = (const short8*)(packM + (size_t)b * 4096);
  f32x4 acc[4];
#pragma unroll
  for (int t = 0; t < 4; t++) acc[t] = (f32x4)(0.f);
#pragma unroll
  for (int t = 0; t < 4; t++){
    short8 b0 = bm[(t * 2 + 0) * 64 + lane];
    short8 b1 = bm[(t * 2 + 1) * 64 + lane];
    acc[t] = __builtin_amdgcn_mfma_f32_16x16x32_bf16(a0, b0, acc[t], 0, 0, 0);
    acc[t] = __builtin_amdgcn_mfma_f32_16x16x32_bf16(a1, b1, acc[t], 0, 0, 0);
  }
#pragma unroll
  for (int t = 0; t < 4; t++){
    int c = t * 16 + m;
    float bias = bprojf[c];
#pragma unroll
    for (int r = 0; r < 4; r++){
      int op = wave * 16 + quad * 4 + r;
      sOut[op][c] = acc[t][r] + bias + bf2f(sP2[c][op]);
    }
  }
  __syncthreads();
  int hi = tid >> 4, lo = tid & 15;
#pragma unroll
  for (int k = 0; k < 4; k++){
    int pos = k * 16 + hi;
    int c0  = lo * 4;
    float4 v = *(const float4*)&sOut[pos][c0];
    *(float4*)(out + (size_t)(pbase + pos) * 64 + c0) = v;
  }
}

extern "C" void kernel_launch(void* const* d_in, const int* in_sizes, int n_in,
                              void* d_out, int out_size, void* d_ws, size_t ws_size,
                              hipStream_t stream){
  (void)in_sizes; (void)n_in; (void)out_size; (void)ws_size;
  const void* x      = d_in[0];
  const void* Wq     = d_in[1];
  const void* Wk     = d_in[2];
  const void* Wv     = d_in[3];
  const void* rescale= d_in[4];
  const void* Wproj  = d_in[5];
  const void* bproj  = d_in[6];
  const void* Wpos1  = d_in[7];
  const void* Wpos2  = d_in[8];

  char* ws = (char*)d_ws;
  u16* p1T   = (u16*)(ws + OFF_P1);
  u16* p2T   = (u16*)(ws + OFF_P2);
  u16* vT    = (u16*)(ws + OFF_V);
  u16* packW = (u16*)(ws + OFF_PW);
  u16* packM = (u16*)(ws + OFF_PM);
  int* flag  = (int*)(ws + OFF_FLAG);
  float* cw  = (float*)(ws + OFF_CW);
  float* part= (float*)(ws + OFF_PART);
  float* Sp  = part + SP_F;
  float* wqk = part + WQ_F;
  float* out = (float*)d_out;

  k_prep<<<48, 256, 0, stream>>>(x, Wproj, rescale, bproj, Wpos1, Wpos2, Wq, Wk, Wv,
                                 flag, cw, Sp, packW);
  k_qkv<<<NTOT / 1024, 512, 0, stream>>>(x, flag, packW, vT, Sp);
  k_attn_h<<<8, 256, 0, stream>>>(Sp, wqk, cw, packM);
  k_dwconv<true><<<dim3(64, 16, 2), 256, 0, stream>>>(vT, cw + CW_WPOS1, p1T);
  k_dwconv<false><<<dim3(64, 16, 2), 256, 0, stream>>>(p1T, cw + CW_WPOS2, p2T);
  k_final<<<NTOT / 64, 256, 0, stream>>>(vT, packM, cw + CW_BPROJ, p2T, out);
}